// Round 9
// baseline (855.119 us; speedup 1.0000x reference)
//
#include <hip/hip_runtime.h>
#include <hip/hip_bf16.h>

// MPS chain: y[b,c] over 784 sites, chi=64, d=2, 10 ch, batch 1024.
// R9: kill the L1-bandwidth binder (R8: 640 waves x 12.85 MB = 8.2 GB through
// L1 = 80% of aggregate L1 BW). 160 blocks x 4 waves; the 4 waves (4 batch-
// tiles, same channel) SHARE one A-stream: 16 KB/site staged once per block
// via global_load_lds into 3 rotating LDS buffers (distance-2), counted
// s_waitcnt vmcnt(4) + raw s_barrier per site (never vmcnt(0)). Waves read
// frags from LDS (f*1024B + lane*16B: 2-way bank aliasing = free). t-state
// stays lane-local in VGPRs (R6 P-relabeling: MFMA D == next-site B-frag).
// vmcnt ledger (per wave): body n top: stage(n+2) (+4 gload_lds). Group top:
// +2 x-loads. Body end: outstanding 8 (+2) -> vmcnt(4) drains site n+1's 4
// (and x), leaves n+2's 4 in flight. Prologue: x(2),st0(4),st1(4) ->
// vmcnt(4) drains x+st0. Buffers: body n reads buf[n%3], stages buf[(n+2)%3].
// P(mt,mu) = 32*(mt>>1) + 8*(mu>>2) + 4*(mt&1) + (mu&3).
// Layouts (verified R1-R8): A-op m=l&15, k=8*(l>>4)+j; B-op col=l&15, same k;
// D row=4*(l>>4)+r, col=l&15.

#define LEN 784
#define NCH 10

typedef short bf16x8 __attribute__((ext_vector_type(8)));
typedef float f32x4  __attribute__((ext_vector_type(4)));

#define WSA_SHORTS ((size_t)NCH * LEN * 8192)
#define WSX_FLOATS ((size_t)1024 * 2 * LEN)
#define WS_NEED (WSA_SHORTS * 2 + WSX_FLOATS * 4)

#define XSCALE -2.88539008177792681f   // -2*log2(e)
#define XUNDO  -0.34657359027997264f   // 1/XSCALE

static __device__ __forceinline__ unsigned short f2bf(float f) {
    union { __hip_bfloat16 h; unsigned short s; } u;
    u.h = __float2bfloat16(f);
    return u.s;
}

static __device__ __forceinline__ int site_dlim(int m) {
    int e1 = m < 6 ? (1 << m) : 64;
    int e2 = (LEN - m) < 6 ? (1 << (LEN - m)) : 64;
    return e1 < e2 ? e1 : e2;
}

// ---- pre-pass: tensors -> bf16 frag-order wsA (P-permuted m, masked rows),
//      x -> wsX[b][2n+i] pre-scaled by -2*log2(e) ----
__global__ __launch_bounds__(1024) void prepass(const float* __restrict__ x,
                                                const float* __restrict__ tens,
                                                short* __restrict__ wsA,
                                                float* __restrict__ wsX)
{
    const int bid = blockIdx.x;
    const int t = threadIdx.x;
    if (bid < NCH * LEN) {
        const int site = bid % LEN;
        const int dlim = site_dlim(site);
        const int mt = t >> 8, ii = (t >> 7) & 1, kf = (t >> 6) & 1, l = t & 63;
        const int l15 = l & 15;
        const int bout = 32 * (mt >> 1) + 8 * (l15 >> 2) + 4 * (mt & 1) + (l15 & 3);
        const int a0 = 32 * kf + 8 * (l >> 4);
        const float* src = tens + (size_t)bid * 8192;   // [a][i][bout]
        unsigned int wv[4];
        #pragma unroll
        for (int p = 0; p < 4; ++p) {
            int aA = a0 + 2 * p, aB = a0 + 2 * p + 1;
            float f0 = (aA < dlim) ? src[(size_t)aA * 128 + ii * 64 + bout] : 0.f;
            float f1 = (aB < dlim) ? src[(size_t)aB * 128 + ii * 64 + bout] : 0.f;
            wv[p] = (unsigned)f2bf(f0) | ((unsigned)f2bf(f1) << 16);
        }
        *(int4*)(wsA + (size_t)bid * 8192 + (size_t)t * 8) = *(int4*)wv;
    } else {
        int b = bid - NCH * LEN;
        if (t < LEN) {
            float v0 = x[(size_t)b * (2 * LEN) + t] * XSCALE;
            float v1 = x[(size_t)b * (2 * LEN) + LEN + t] * XSCALE;
            float2 pk; pk.x = v0; pk.y = v1;
            *(float2*)(wsX + (size_t)b * (2 * LEN) + 2 * t) = pk;
        }
    }
}

// ---- main chain kernel: 4 waves share one A-stream via LDS ----
__global__ __launch_bounds__(256) void mps_fwd9(const short* __restrict__ wsA,
                                                const float* __restrict__ wsX,
                                                float* __restrict__ out)
{
    __shared__ short Abuf[3][8192];   // 3 x 16 KB rotating site buffers

    const int tid = threadIdx.x;
    const int lane = tid & 63;
    const int wv = tid >> 6;          // wave 0..3 = batch-tile within block
    const int g = lane >> 4, l15 = lane & 15;

    // XCD-aware: 160 = 8 XCDs x 20; each XCD spans <=2 channels
    const int p = blockIdx.x;
    const int gidx = (p & 7) * 20 + (p >> 3);
    const int ch = gidx >> 4;                 // 0..9
    const int b0 = (gidx & 15) * 64 + wv * 16;

    const short* asrc = wsA + (size_t)ch * LEN * 8192;
    const float* xsrc = wsX + (size_t)(b0 + l15) * (2 * LEN);

    // t-state in registers: tf[kf][j] = t[32kf + 8g + j] for col l15
    bf16x8 tf0, tf1;
    #pragma unroll
    for (int j = 0; j < 8; ++j) { tf0[j] = 0; tf1[j] = 0; }
    if (g == 0) tf0[0] = (short)0x3F80;

    // stage one site (16 KB) into buf: this wave covers 4 KB = 4 gload_lds
    auto stage = [&](int site, int buf) {
        site = site < LEN ? site : LEN - 1;
        const short* sb = asrc + (size_t)site * 8192 + (size_t)wv * 2048 + lane * 8;
        short* db = &Abuf[buf][wv * 2048];
        #pragma unroll
        for (int k = 0; k < 4; ++k)
            __builtin_amdgcn_global_load_lds(
                (const __attribute__((address_space(1))) unsigned int*)(sb + k * 512),
                (__attribute__((address_space(3))) unsigned int*)(db + k * 512),
                16, 0, 0);
    };

    auto loadX = [&](int nb, float4& qa, float4& qb) {
        nb = nb <= LEN - 4 ? nb : LEN - 4;
        const float* sx = xsrc + 2 * nb;
        asm volatile("global_load_dwordx4 %0, %1, off" : "=v"(qa) : "v"(sx));
        asm volatile("global_load_dwordx4 %0, %1, off offset:16" : "=v"(qb) : "v"(sx));
    };

    #define WAITBAR() do { \
        asm volatile("s_waitcnt vmcnt(4)\n\ts_barrier" ::: "memory"); \
        __builtin_amdgcn_sched_barrier(0); \
    } while (0)

    auto body = [&](int n, float x0s, float x1s) {
        // (1) distance-2 staging into buf[(n+2)%3]
        stage(n + 2, (n + 2) % 3);
        __builtin_amdgcn_sched_barrier(0);

        // (2) read this site's frags from buf[n%3] + 16 MFMA
        const short* fb = &Abuf[n % 3][lane * 8];
        f32x4 acc[4][2];    // [mt][ii]
        #pragma unroll
        for (int mt = 0; mt < 4; ++mt)
            #pragma unroll
            for (int ii = 0; ii < 2; ++ii)
                acc[mt][ii] = (f32x4){0.f, 0.f, 0.f, 0.f};

        #pragma unroll
        for (int kf = 0; kf < 2; ++kf) {
            bf16x8 tfk = kf ? tf1 : tf0;
            #pragma unroll
            for (int mt = 0; mt < 4; ++mt)
                #pragma unroll
                for (int ii = 0; ii < 2; ++ii)
                    acc[mt][ii] = __builtin_amdgcn_mfma_f32_16x16x32_bf16(
                        *(const bf16x8*)(fb + (size_t)(mt * 4 + ii * 2 + kf) * 512),
                        tfk, acc[mt][ii], 0, 0, 0);
        }

        // (3) epilogue: x-combine + sigmoid -> next t frags (mask is in wsA)
        if (n == LEN - 1) {
            if (g == 0) {
                float v = (x0s * acc[0][0][0] + x1s * acc[0][1][0]) * XUNDO;
                out[(size_t)(b0 + l15) * NCH + ch] = v;
            }
        } else {
            unsigned pk[8];   // [mt][rpair]
            #pragma unroll
            for (int mt = 0; mt < 4; ++mt)
                #pragma unroll
                for (int rp = 0; rp < 2; ++rp) {
                    unsigned short sv[2];
                    #pragma unroll
                    for (int q2 = 0; q2 < 2; ++q2) {
                        int r = 2 * rp + q2;
                        float u = x0s * acc[mt][0][r] + x1s * acc[mt][1][r];
                        float sg = __builtin_amdgcn_rcpf(1.0f + exp2f(u));
                        sv[q2] = f2bf(sg);
                    }
                    pk[mt * 2 + rp] = (unsigned)sv[0] | ((unsigned)sv[1] << 16);
                }
            union { unsigned u[4]; bf16x8 v; } u0, u1;
            u0.u[0] = pk[0]; u0.u[1] = pk[1]; u0.u[2] = pk[2]; u0.u[3] = pk[3];
            u1.u[0] = pk[4]; u1.u[1] = pk[5]; u1.u[2] = pk[6]; u1.u[3] = pk[7];
            tf0 = u0.v; tf1 = u1.v;
        }

        // (4) counted wait (site n+1's staging done) + barrier
        WAITBAR();
    };

    float4 xa, xb, xna, xnb;
    loadX(0, xa, xb);     // 2 loads
    stage(0, 0);          // 4
    stage(1, 1);          // 4 -> outstanding 10
    WAITBAR();            // drains x + stage0; stage1 in flight

    for (int nb = 0; nb < LEN; nb += 4) {
        loadX(nb + 4, xna, xnb);
        body(nb + 0, xa.x, xa.y);
        body(nb + 1, xa.z, xa.w);
        body(nb + 2, xb.x, xb.y);
        body(nb + 3, xb.z, xb.w);
        xa = xna; xb = xnb;
    }
    #undef WAITBAR
}

// ---- fallback (ws too small): R8 plain path, reads raw inputs ----
__global__ __launch_bounds__(64) void mps_fwd9_fb(const float* __restrict__ x,
                                                  const float* __restrict__ tens,
                                                  float* __restrict__ out)
{
    const int lane = threadIdx.x;
    const int g = lane >> 4, l15 = lane & 15;
    const int p = blockIdx.x;
    const int gidx = (p & 7) * 80 + (p >> 3);
    const int ch = gidx >> 6;
    const int b0 = (gidx & 63) * 16;

    const float* tsrc = tens + (size_t)ch * LEN * 8192;
    const float* xsrc = x + (size_t)(b0 + l15) * (2 * LEN);

    bf16x8 tf0, tf1;
    #pragma unroll
    for (int j = 0; j < 8; ++j) { tf0[j] = 0; tf1[j] = 0; }
    if (g == 0) tf0[0] = (short)0x3F80;

    for (int n = 0; n < LEN; ++n) {
        const int dlim = site_dlim(n);
        const float* sb = tsrc + (size_t)n * 8192;
        bf16x8 A[16];
        #pragma unroll
        for (int f = 0; f < 16; ++f) {
            int mt = f >> 2, ii = (f >> 1) & 1, kf = f & 1;
            int bout = 32 * (mt >> 1) + 8 * (l15 >> 2) + 4 * (mt & 1) + (l15 & 3);
            int a0 = 32 * kf + 8 * g;
            unsigned int wv[4];
            #pragma unroll
            for (int q2 = 0; q2 < 4; ++q2) {
                int aA = a0 + 2 * q2, aB = aA + 1;
                float f0 = (aA < dlim) ? sb[(size_t)aA * 128 + ii * 64 + bout] : 0.f;
                float f1 = (aB < dlim) ? sb[(size_t)aB * 128 + ii * 64 + bout] : 0.f;
                wv[q2] = (unsigned)f2bf(f0) | ((unsigned)f2bf(f1) << 16);
            }
            A[f] = *(bf16x8*)wv;
        }
        float x0s = xsrc[n] * XSCALE, x1s = xsrc[LEN + n] * XSCALE;

        f32x4 acc[4][2];
        #pragma unroll
        for (int mt = 0; mt < 4; ++mt)
            #pragma unroll
            for (int ii = 0; ii < 2; ++ii)
                acc[mt][ii] = (f32x4){0.f, 0.f, 0.f, 0.f};
        #pragma unroll
        for (int kf = 0; kf < 2; ++kf) {
            bf16x8 tfk = kf ? tf1 : tf0;
            #pragma unroll
            for (int mt = 0; mt < 4; ++mt)
                #pragma unroll
                for (int ii = 0; ii < 2; ++ii)
                    acc[mt][ii] = __builtin_amdgcn_mfma_f32_16x16x32_bf16(
                        A[mt * 4 + ii * 2 + kf], tfk, acc[mt][ii], 0, 0, 0);
        }

        if (n == LEN - 1) {
            if (g == 0) {
                float v = (x0s * acc[0][0][0] + x1s * acc[0][1][0]) * XUNDO;
                out[(size_t)(b0 + l15) * NCH + ch] = v;
            }
        } else {
            unsigned pk[8];
            #pragma unroll
            for (int mt = 0; mt < 4; ++mt)
                #pragma unroll
                for (int rp = 0; rp < 2; ++rp) {
                    unsigned short sv[2];
                    #pragma unroll
                    for (int q2 = 0; q2 < 2; ++q2) {
                        int r = 2 * rp + q2;
                        float u = x0s * acc[mt][0][r] + x1s * acc[mt][1][r];
                        float sg = __builtin_amdgcn_rcpf(1.0f + exp2f(u));
                        sv[q2] = f2bf(sg);
                    }
                    pk[mt * 2 + rp] = (unsigned)sv[0] | ((unsigned)sv[1] << 16);
                }
            union { unsigned u[4]; bf16x8 v; } u0, u1;
            u0.u[0] = pk[0]; u0.u[1] = pk[1]; u0.u[2] = pk[2]; u0.u[3] = pk[3];
            u1.u[0] = pk[4]; u1.u[1] = pk[5]; u1.u[2] = pk[6]; u1.u[7 - 7] = u1.u[0]; // no-op keep layout
            u1.u[0] = pk[4]; u1.u[1] = pk[5]; u1.u[2] = pk[6]; u1.u[3] = pk[7];
            tf0 = u0.v; tf1 = u1.v;
        }
    }
}

extern "C" void kernel_launch(void* const* d_in, const int* in_sizes, int n_in,
                              void* d_out, int out_size, void* d_ws, size_t ws_size,
                              hipStream_t stream) {
    (void)in_sizes; (void)n_in; (void)out_size;
    const float* x    = (const float*)d_in[0];
    const float* tens = (const float*)d_in[1];
    float* out = (float*)d_out;
    if (ws_size >= WS_NEED) {
        short* wsA = (short*)d_ws;
        float* wsX = (float*)((char*)d_ws + WSA_SHORTS * 2);
        hipLaunchKernelGGL(prepass, dim3(NCH * LEN + 1024), dim3(1024), 0, stream,
                           x, tens, wsA, wsX);
        hipLaunchKernelGGL(mps_fwd9, dim3(160), dim3(256), 0, stream,
                           wsA, wsX, out);
    } else {
        hipLaunchKernelGGL(mps_fwd9_fb, dim3(640), dim3(64), 0, stream,
                           x, tens, out);
    }
}